// Round 11
// baseline (167325.684 us; speedup 1.0000x reference)
//
#include <hip/hip_runtime.h>
#include <cstdint>
#include <cstddef>

// SokobanNCA v11: balanced 2-way-read partition. Wave (mh,qh): main trio
// qt{4qh..4qh+2} x mt quad 4mh..4mh+3, PLUS odd tile qt3 x 2 mt
// (4mh+2qh,+1). 14 units/wave = 56 MFMA/layer (r6's balanced crit path)
// with r10's halved LDS reads (trios 2x, qt3 4x). No partial sums.

#define NSAMPLES 2048
#define ZROW_BASE 28672          // 112*256
#define HA_OFF 0
#define HB_OFF 28928             // 113*256
#define A1_OFF HB_OFF            // A1 aliases hB (disjoint lifetime)
#define XS_OFF 57600             // HB_OFF + 112*256
#define LDS_TOTAL 62976          // XS_OFF + 112*48

typedef __attribute__((ext_vector_type(8))) short bf16x8;
typedef __attribute__((ext_vector_type(4))) float f32x4;
typedef __attribute__((ext_vector_type(2))) unsigned int u32x2;
typedef __attribute__((ext_vector_type(4))) unsigned int u32x4;

#define MFMA16(A,B,C) __builtin_amdgcn_mfma_f32_16x16x32_bf16((A),(B),(C),0,0,0)

__device__ __forceinline__ unsigned pk2(float a, float b) {
  unsigned r;
  asm("v_cvt_pk_bf16_f32 %0, %1, %2" : "=v"(r) : "v"(a), "v"(b));
  return r;
}
__device__ __forceinline__ unsigned pk2r(float a, float b) {
  return pk2(fmaxf(a, 0.f), fmaxf(b, 0.f));
}

__device__ __forceinline__ short f2bf(float f) {
  unsigned u = __float_as_uint(f);
  return (short)((u + 0x7FFFu + ((u >> 16) & 1u)) >> 16);  // RNE
}

// ---------------- weight pre-pack (unchanged; validated r1-r10) ----------------
__global__ void prepack_kernel(const float* __restrict__ w, short* __restrict__ dst,
                               int mode, int ntc, int Kact, int Nact, int total) {
  int idx = blockIdx.x * 256 + threadIdx.x;
  if (idx >= total) return;
  int j = idx & 7, l = (idx >> 3) & 63, t = idx >> 9;
  int nt = t % ntc, kt = t / ntc;
  int kg = kt * 32 + (l >> 4) * 8 + j;
  int nn = nt * 16 + (l & 15);
  float v = 0.f;
  if (mode == 0) {
    if (kg < Kact && nn < Nact) v = w[nn * Kact + kg];
  } else if (mode == 1) {
    if (kg < 45) { int s = kg / 5, cin = kg - 5 * s; v = w[nn * 45 + cin * 9 + s]; }
  } else {
    int s = kt >> 2;
    int kk = (kt & 3) * 32 + (l >> 4) * 8 + j;
    v = w[nn * 1152 + kk * 9 + s];
  }
  dst[idx] = f2bf(v);
}

// ---------------- main kernel ----------------
__global__ __launch_bounds__(256, 2)
void nca_kernel(
    const float* __restrict__ x_in,
    const float* __restrict__ b1p, const float* __restrict__ b2p,
    const float* __restrict__ b3p, const float* __restrict__ b4p,
    const float* __restrict__ b5p, const float* __restrict__ b6p,
    const float* __restrict__ b7p,
    const short* __restrict__ W1, const short* __restrict__ W2,
    const short* __restrict__ W3,   // W3..W6 contiguous: W3 + li*16384
    const short* __restrict__ W7,
    const int* __restrict__ steps_ptr, float* __restrict__ d_out) {
  __shared__ __align__(16) char lds[LDS_TOTAL];
  float* xs = (float*)(lds + XS_OFF);  // [112][12] f32, rows 48 B

  const int tid = threadIdx.x;
  const int sample = blockIdx.x;
  const int w = tid >> 6;         // wave 0..3
  const int mh = w >> 1;          // c_out quad: tiles 4mh..4mh+3
  const int qh = w & 1;           // qt group
  const int l = tid & 63;
  const int n = l & 15;
  const int g = l >> 4;
  const int g16 = g << 4;
  const int swzc = (n & 7) << 4;
  const int qb = qh * 4;          // main trio base: {qb, qb+1, qb+2}
  const int me = 2 * qh;          // extra tile's local mt indices {me, me+1}
  const int steps = *steps_ptr;
  const float steps_f = (float)steps;
  const f32x4 fz = {0.f, 0.f, 0.f, 0.f};

  // LDS bases (layout identical to r3-r10)
  const int rdA = HA_OFF + n * 256 + (g16 ^ swzc);
  const int rdB = HB_OFF + n * 256 + (g16 ^ swzc);
  const int rd1 = A1_OFF + n * 128 + (g16 ^ swzc);
  const int za  = HA_OFF + ZROW_BASE + g16;
  int wcolv[4];
#pragma unroll
  for (int i = 0; i < 4; ++i)
    wcolv[i] = ((32 * (4 * mh + i)) | (8 * g)) ^ swzc;

  // pixel geometry: main trio + extra tile qt3 (c2 shift masking)
  int rcm[3], rc3;
#pragma unroll
  for (int qtl = 0; qtl < 3; ++qtl) {
    int p = 16 * (qb + qtl) + n;
    if (p < 100) { int r = p / 10; rcm[qtl] = r * 32 + (p - 10 * r); }
    else rcm[qtl] = 0x4000;
  }
  { int p = 48 + n; int r = p / 10; rc3 = r * 32 + (p - 10 * r); }

  // strided (c,px) decomposition for 500-elem copies
  const int cA = tid / 100, pA = tid - 100 * cA;
  const int cB = (tid + 256) / 100, pB = tid + 256 - 100 * cB;
  const int offA = pA * 12 + cA, offB = pB * 12 + cB;

  // zero ZROW of hA
  if (tid < 64) *(unsigned*)(lds + HA_OFF + ZROW_BASE + tid * 4) = 0;
  // load x state
  xs[offA] = x_in[(size_t)sample * 500 + tid];
  if (tid < 244) xs[offB] = x_in[(size_t)sample * 500 + tid + 256];
  // resident c7 bias (tiny)
  f32x4 b7v = fz;
  if (g == 0) b7v = *(const f32x4*)&b7p[0];
  else if (g == 1) b7v.x = b7p[4];
  __syncthreads();

  for (int step = 0; step < steps; ++step) {
    // ---- phase A: copy out states[step-1]; build im2col (r6-validated) ----
    if (step > 0) {
      size_t sb = 1024000u + ((size_t)(step - 1) * NSAMPLES + sample) * 500u;
      __builtin_nontemporal_store(xs[offA], &d_out[sb + tid]);
      if (tid < 244) __builtin_nontemporal_store(xs[offB], &d_out[sb + tid + 256]);
    }
    if (tid < 112) {
      const int p = tid;
      const bool pv = p < 100;
      const int pc = pv ? p : 99;
      const int r = pc / 10, c0 = pc - 10 * r;
      float val[48];
#pragma unroll
      for (int s = 0; s < 9; ++s) {
        const int dr = s / 3 - 1, dc = s % 3 - 1;
        f32x4 xv = fz; float x4v = 0.f;
        if (pv && (unsigned)(r + dr) < 10u && (unsigned)(c0 + dc) < 10u) {
          const float* xr = &xs[(p + dr * 10 + dc) * 12];
          xv = *(const f32x4*)xr; x4v = xr[4];
        }
        val[5*s+0] = xv.x; val[5*s+1] = xv.y; val[5*s+2] = xv.z;
        val[5*s+3] = xv.w; val[5*s+4] = x4v;
      }
      val[45] = val[46] = val[47] = 0.f;
      unsigned wd[24];
#pragma unroll
      for (int i = 0; i < 24; ++i) wd[i] = pk2(val[2*i], val[2*i+1]);
      const int swzr = (p & 7) << 4;
      char* arow = lds + A1_OFF + p * 128;
#pragma unroll
      for (int j = 0; j < 6; ++j) {
        u32x4 wv = {wd[4*j], wd[4*j+1], wd[4*j+2], wd[4*j+3]};
        *(u32x4*)(arow + ((16 * j) ^ swzr)) = wv;
      }
      u32x4 z4 = {0, 0, 0, 0};
      *(u32x4*)(arow + (96 ^ swzr)) = z4;
      *(u32x4*)(arow + (112 ^ swzr)) = z4;
    }
    __syncthreads();

    // ---- c1: A1 @ W1 (K=64) -> hA (main trio x quad + extra qt3 x 2mt) ----
    {
      f32x4 pbv[4];
#pragma unroll
      for (int i = 0; i < 4; ++i)
        pbv[i] = *(const f32x4*)&b1p[16 * (4 * mh + i) + 4 * g];
      f32x4 accm[4][3], acce[2];
#pragma unroll
      for (int i = 0; i < 4; ++i)
#pragma unroll
        for (int qtl = 0; qtl < 3; ++qtl) accm[i][qtl] = pbv[i];
      acce[0] = pbv[me]; acce[1] = pbv[me + 1];
#pragma unroll
      for (int kt = 0; kt < 2; ++kt) {
        bf16x8 Wf[4];
#pragma unroll
        for (int i = 0; i < 4; ++i)
          Wf[i] = *(const bf16x8*)&W1[((kt * 8 + 4 * mh + i) * 64 + l) * 8];
        const char* src = lds + (rd1 ^ (kt << 6));
#pragma unroll
        for (int qtl = 0; qtl < 3; ++qtl) {
          bf16x8 Bf = *(const bf16x8*)(src + (qb + qtl) * 2048);
#pragma unroll
          for (int i = 0; i < 4; ++i) accm[i][qtl] = MFMA16(Wf[i], Bf, accm[i][qtl]);
        }
        bf16x8 Be = *(const bf16x8*)(src + 3 * 2048);
        acce[0] = MFMA16(Wf[me], Be, acce[0]);
        acce[1] = MFMA16(Wf[me + 1], Be, acce[1]);
      }
#pragma unroll
      for (int qtl = 0; qtl < 3; ++qtl) {
        int row = (16 * (qb + qtl) + n) * 256;
#pragma unroll
        for (int i = 0; i < 4; ++i) {
          f32x4 v = accm[i][qtl];
          u32x2 wv = {pk2r(v.x, v.y), pk2r(v.z, v.w)};
          *(u32x2*)(lds + HA_OFF + row + wcolv[i]) = wv;
        }
      }
      {
        int row = (48 + n) * 256;
#pragma unroll
        for (int i = 0; i < 2; ++i) {
          f32x4 v = acce[i];
          u32x2 wv = {pk2r(v.x, v.y), pk2r(v.z, v.w)};
          *(u32x2*)(lds + HA_OFF + row + wcolv[me + i]) = wv;
        }
      }
    }
    __syncthreads();

    // ---- c2: 3x3 shift-decomposed, runtime s-loop ----
    {
      f32x4 pbv[4];
#pragma unroll
      for (int i = 0; i < 4; ++i)
        pbv[i] = *(const f32x4*)&b2p[16 * (4 * mh + i) + 4 * g];
      f32x4 accm[4][3], acce[2];
#pragma unroll
      for (int i = 0; i < 4; ++i)
#pragma unroll
        for (int qtl = 0; qtl < 3; ++qtl) accm[i][qtl] = pbv[i];
      acce[0] = pbv[me]; acce[1] = pbv[me + 1];
#pragma unroll 1
      for (int s = 0; s < 9; ++s) {
        const int s3 = s / 3;
        const int dr = s3 - 1, dc = s - 3 * s3 - 1;
        const int ps = n + dr * 10 + dc;
        const int bs = HA_OFF + ps * 256 + (g16 ^ ((ps & 7) << 4));
        int vam[3], vae;
#pragma unroll
        for (int qtl = 0; qtl < 3; ++qtl) {
          bool ok = ((unsigned)((rcm[qtl] >> 5) + dr) < 10u) &&
                    ((unsigned)((rcm[qtl] & 31) + dc) < 10u);
          vam[qtl] = ok ? (bs + (qb + qtl) * 4096) : za;
        }
        {
          bool ok = ((unsigned)((rc3 >> 5) + dr) < 10u) &&
                    ((unsigned)((rc3 & 31) + dc) < 10u);
          vae = ok ? (bs + 3 * 4096) : za;
        }
        const short* Wsl = W2 + s * 16384;
#pragma unroll
        for (int kt = 0; kt < 4; ++kt) {
          bf16x8 Wf[4];
#pragma unroll
          for (int i = 0; i < 4; ++i)
            Wf[i] = *(const bf16x8*)&Wsl[((kt * 8 + 4 * mh + i) * 64 + l) * 8];
#pragma unroll
          for (int qtl = 0; qtl < 3; ++qtl) {
            bf16x8 Bf = *(const bf16x8*)(lds + (vam[qtl] ^ (kt << 6)));
#pragma unroll
            for (int i = 0; i < 4; ++i) accm[i][qtl] = MFMA16(Wf[i], Bf, accm[i][qtl]);
          }
          bf16x8 Be = *(const bf16x8*)(lds + (vae ^ (kt << 6)));
          acce[0] = MFMA16(Wf[me], Be, acce[0]);
          acce[1] = MFMA16(Wf[me + 1], Be, acce[1]);
        }
      }
#pragma unroll
      for (int qtl = 0; qtl < 3; ++qtl) {
        int row = (16 * (qb + qtl) + n) * 256;
#pragma unroll
        for (int i = 0; i < 4; ++i) {
          f32x4 v = accm[i][qtl];
          u32x2 wv = {pk2r(v.x, v.y), pk2r(v.z, v.w)};
          *(u32x2*)(lds + HB_OFF + row + wcolv[i]) = wv;
        }
      }
      {
        int row = (48 + n) * 256;
#pragma unroll
        for (int i = 0; i < 2; ++i) {
          f32x4 v = acce[i];
          u32x2 wv = {pk2r(v.x, v.y), pk2r(v.z, v.w)};
          *(u32x2*)(lds + HB_OFF + row + wcolv[me + i]) = wv;
        }
      }
    }
    __syncthreads();

    // ---- c3..c6: runtime layer loop, ping-pong hB<->hA ----
#pragma unroll 1
    for (int li = 0; li < 4; ++li) {
      const float* bp = (li == 0) ? b3p : (li == 1) ? b4p : (li == 2) ? b5p : b6p;
      const int rdb = (li & 1) ? rdA : rdB;
      const int dsto = (li & 1) ? HB_OFF : HA_OFF;
      const short* Wp = W3 + li * 16384;
      f32x4 pbv[4];
#pragma unroll
      for (int i = 0; i < 4; ++i)
        pbv[i] = *(const f32x4*)&bp[16 * (4 * mh + i) + 4 * g];
      f32x4 accm[4][3], acce[2];
#pragma unroll
      for (int i = 0; i < 4; ++i)
#pragma unroll
        for (int qtl = 0; qtl < 3; ++qtl) accm[i][qtl] = pbv[i];
      acce[0] = pbv[me]; acce[1] = pbv[me + 1];
#pragma unroll
      for (int kt = 0; kt < 4; ++kt) {
        bf16x8 Wf[4];
#pragma unroll
        for (int i = 0; i < 4; ++i)
          Wf[i] = *(const bf16x8*)&Wp[((kt * 8 + 4 * mh + i) * 64 + l) * 8];
        const char* src = lds + (rdb ^ (kt << 6));
#pragma unroll
        for (int qtl = 0; qtl < 3; ++qtl) {
          bf16x8 Bf = *(const bf16x8*)(src + (qb + qtl) * 4096);
#pragma unroll
          for (int i = 0; i < 4; ++i) accm[i][qtl] = MFMA16(Wf[i], Bf, accm[i][qtl]);
        }
        bf16x8 Be = *(const bf16x8*)(src + 3 * 4096);
        acce[0] = MFMA16(Wf[me], Be, acce[0]);
        acce[1] = MFMA16(Wf[me + 1], Be, acce[1]);
      }
#pragma unroll
      for (int qtl = 0; qtl < 3; ++qtl) {
        int row = (16 * (qb + qtl) + n) * 256;
#pragma unroll
        for (int i = 0; i < 4; ++i) {
          f32x4 v = accm[i][qtl];
          u32x2 wv = {pk2r(v.x, v.y), pk2r(v.z, v.w)};
          *(u32x2*)(lds + dsto + row + wcolv[i]) = wv;
        }
      }
      {
        int row = (48 + n) * 256;
#pragma unroll
        for (int i = 0; i < 2; ++i) {
          f32x4 v = acce[i];
          u32x2 wv = {pk2r(v.x, v.y), pk2r(v.z, v.w)};
          *(u32x2*)(lds + dsto + row + wcolv[me + i]) = wv;
        }
      }
      __syncthreads();
    }

    // ---- c7 (128->5) + residual + softmax (r6-validated, W7f transient) ----
    {
      bf16x8 W7f[4];
#pragma unroll
      for (int kt = 0; kt < 4; ++kt)
        W7f[kt] = *(const bf16x8*)&W7[(kt * 64 + l) * 8];
      float invT = 1.f / fmaxf(1.f - (float)step / steps_f, 0.5f);
#pragma unroll
      for (int rep = 0; rep < 2; ++rep) {
        int qt = 2 * w + rep;
        if (qt < 7) {
          f32x4 a = b7v;
          int va7 = rdB + qt * 4096;
#pragma unroll
          for (int kt = 0; kt < 4; ++kt) {
            bf16x8 Bf = *(const bf16x8*)(lds + (va7 ^ (kt << 6)));
            a = MFMA16(W7f[kt], Bf, a);
          }
          float c4v = __shfl_xor(a.x, 16);
          int px = 16 * qt + n;
          if (g == 0 && px < 100) {
            float* xr = &xs[px * 12];
            f32x4 xo = *(f32x4*)xr; float x4 = xr[4];
            float v0 = (xo.x + a.x) * invT, v1 = (xo.y + a.y) * invT;
            float v2 = (xo.z + a.z) * invT, v3 = (xo.w + a.w) * invT;
            float v4 = (x4 + c4v) * invT;
            float m = fmaxf(fmaxf(fmaxf(v0, v1), fmaxf(v2, v3)), v4);
            float e0 = __expf(v0 - m), e1 = __expf(v1 - m), e2 = __expf(v2 - m);
            float e3 = __expf(v3 - m), e4 = __expf(v4 - m);
            float inv = 1.f / (e0 + e1 + e2 + e3 + e4);
            f32x4 pv = {e0 * inv, e1 * inv, e2 * inv, e3 * inv};
            *(f32x4*)xr = pv; xr[4] = e4 * inv;
          }
        }
      }
    }
    __syncthreads();
  }

  // ---- final outputs: x_final + states[steps-1] (nontemporal) ----
  {
    size_t sb = 1024000u + ((size_t)(steps - 1) * NSAMPLES + sample) * 500u;
    size_t fb = (size_t)sample * 500u;
    float vA = xs[offA];
    __builtin_nontemporal_store(vA, &d_out[fb + tid]);
    __builtin_nontemporal_store(vA, &d_out[sb + tid]);
    if (tid < 244) {
      float vB = xs[offB];
      __builtin_nontemporal_store(vB, &d_out[fb + tid + 256]);
      __builtin_nontemporal_store(vB, &d_out[sb + tid + 256]);
    }
  }
}

// ---------------- launch ----------------
extern "C" void kernel_launch(void* const* d_in, const int* in_sizes, int n_in,
                              void* d_out, int out_size, void* d_ws, size_t ws_size,
                              hipStream_t stream) {
  const float* x   = (const float*)d_in[0];
  const float* wp1 = (const float*)d_in[1];
  const float* bp1 = (const float*)d_in[2];
  const float* wp2 = (const float*)d_in[3];
  const float* bp2 = (const float*)d_in[4];
  const float* wp3 = (const float*)d_in[5];
  const float* bp3 = (const float*)d_in[6];
  const float* wu1 = (const float*)d_in[7];
  const float* bu1 = (const float*)d_in[8];
  const float* wu2 = (const float*)d_in[9];
  const float* bu2 = (const float*)d_in[10];
  const float* wu3 = (const float*)d_in[11];
  const float* bu3 = (const float*)d_in[12];
  const float* wu4 = (const float*)d_in[13];
  const float* bu4 = (const float*)d_in[14];
  const int* steps = (const int*)d_in[15];

  short* W1 = (short*)d_ws;          // [2][8][512]
  short* W2 = W1 + 8192;             // [36][8][512]
  short* W3 = W2 + 147456;           // 4 x [4][8][512] contiguous
  short* W4 = W3 + 16384;
  short* W5 = W4 + 16384;
  short* W6 = W5 + 16384;
  short* W7 = W6 + 16384;            // [4][1][512]

  prepack_kernel<<<(8192   + 255) / 256, 256, 0, stream>>>(wp1, W1, 1, 8, 45,   128, 8192);
  prepack_kernel<<<(147456 + 255) / 256, 256, 0, stream>>>(wp2, W2, 2, 8, 1152, 128, 147456);
  prepack_kernel<<<(16384  + 255) / 256, 256, 0, stream>>>(wp3, W3, 0, 8, 128,  128, 16384);
  prepack_kernel<<<(16384  + 255) / 256, 256, 0, stream>>>(wu1, W4, 0, 8, 128,  128, 16384);
  prepack_kernel<<<(16384  + 255) / 256, 256, 0, stream>>>(wu2, W5, 0, 8, 128,  128, 16384);
  prepack_kernel<<<(16384  + 255) / 256, 256, 0, stream>>>(wu3, W6, 0, 8, 128,  128, 16384);
  prepack_kernel<<<(2048   + 255) / 256, 256, 0, stream>>>(wu4, W7, 0, 1, 128,  5,   2048);

  nca_kernel<<<NSAMPLES, 256, 0, stream>>>(
      x, bp1, bp2, bp3, bu1, bu2, bu3, bu4,
      W1, W2, W3, W7, steps, (float*)d_out);
}

// Round 12
// 6925.668 us; speedup vs baseline: 24.1602x; 24.1602x over previous
//
#include <hip/hip_runtime.h>
#include <cstdint>
#include <cstddef>

// SokobanNCA v12: r11's balanced 2-way-read partition with ALL runtime
// register-array indexing removed (r11 demoted Wf/pbv/wcolv to scratch ->
// 7.7GB spill traffic, MfmaUtil 1.2%). Extra-tile (qt3) weight fragments are
// loaded directly from global with runtime ADDRESS (L1-hit duplicates of the
// sibling wave's lines); bias/wcol for the extra tile are named scalars.

#define NSAMPLES 2048
#define ZROW_BASE 28672          // 112*256
#define HA_OFF 0
#define HB_OFF 28928             // 113*256
#define A1_OFF HB_OFF            // A1 aliases hB (disjoint lifetime)
#define XS_OFF 57600             // HB_OFF + 112*256
#define LDS_TOTAL 62976          // XS_OFF + 112*48

typedef __attribute__((ext_vector_type(8))) short bf16x8;
typedef __attribute__((ext_vector_type(4))) float f32x4;
typedef __attribute__((ext_vector_type(2))) unsigned int u32x2;
typedef __attribute__((ext_vector_type(4))) unsigned int u32x4;

#define MFMA16(A,B,C) __builtin_amdgcn_mfma_f32_16x16x32_bf16((A),(B),(C),0,0,0)

__device__ __forceinline__ unsigned pk2(float a, float b) {
  unsigned r;
  asm("v_cvt_pk_bf16_f32 %0, %1, %2" : "=v"(r) : "v"(a), "v"(b));
  return r;
}
__device__ __forceinline__ unsigned pk2r(float a, float b) {
  return pk2(fmaxf(a, 0.f), fmaxf(b, 0.f));
}

__device__ __forceinline__ short f2bf(float f) {
  unsigned u = __float_as_uint(f);
  return (short)((u + 0x7FFFu + ((u >> 16) & 1u)) >> 16);  // RNE
}

// ---------------- weight pre-pack (unchanged; validated r1-r11) ----------------
__global__ void prepack_kernel(const float* __restrict__ w, short* __restrict__ dst,
                               int mode, int ntc, int Kact, int Nact, int total) {
  int idx = blockIdx.x * 256 + threadIdx.x;
  if (idx >= total) return;
  int j = idx & 7, l = (idx >> 3) & 63, t = idx >> 9;
  int nt = t % ntc, kt = t / ntc;
  int kg = kt * 32 + (l >> 4) * 8 + j;
  int nn = nt * 16 + (l & 15);
  float v = 0.f;
  if (mode == 0) {
    if (kg < Kact && nn < Nact) v = w[nn * Kact + kg];
  } else if (mode == 1) {
    if (kg < 45) { int s = kg / 5, cin = kg - 5 * s; v = w[nn * 45 + cin * 9 + s]; }
  } else {
    int s = kt >> 2;
    int kk = (kt & 3) * 32 + (l >> 4) * 8 + j;
    v = w[nn * 1152 + kk * 9 + s];
  }
  dst[idx] = f2bf(v);
}

// ---------------- main kernel ----------------
__global__ __launch_bounds__(256, 2)
void nca_kernel(
    const float* __restrict__ x_in,
    const float* __restrict__ b1p, const float* __restrict__ b2p,
    const float* __restrict__ b3p, const float* __restrict__ b4p,
    const float* __restrict__ b5p, const float* __restrict__ b6p,
    const float* __restrict__ b7p,
    const short* __restrict__ W1, const short* __restrict__ W2,
    const short* __restrict__ W3,   // W3..W6 contiguous: W3 + li*16384
    const short* __restrict__ W7,
    const int* __restrict__ steps_ptr, float* __restrict__ d_out) {
  __shared__ __align__(16) char lds[LDS_TOTAL];
  float* xs = (float*)(lds + XS_OFF);  // [112][12] f32, rows 48 B

  const int tid = threadIdx.x;
  const int sample = blockIdx.x;
  const int w = tid >> 6;         // wave 0..3
  const int mh = w >> 1;          // c_out quad: tiles 4mh..4mh+3
  const int qh = w & 1;           // qt group
  const int l = tid & 63;
  const int n = l & 15;
  const int g = l >> 4;
  const int g16 = g << 4;
  const int swzc = (n & 7) << 4;
  const int qb = qh * 4;          // main trio base: {qb, qb+1, qb+2}
  const int mte = 4 * mh + 2 * qh;  // extra tile (qt3): global mt {mte, mte+1}
  const int steps = *steps_ptr;
  const float steps_f = (float)steps;
  const f32x4 fz = {0.f, 0.f, 0.f, 0.f};

  // LDS bases (layout identical to r3-r11)
  const int rdA = HA_OFF + n * 256 + (g16 ^ swzc);
  const int rdB = HB_OFF + n * 256 + (g16 ^ swzc);
  const int rd1 = A1_OFF + n * 128 + (g16 ^ swzc);
  const int za  = HA_OFF + ZROW_BASE + g16;
  int wcolv[4];
#pragma unroll
  for (int i = 0; i < 4; ++i)
    wcolv[i] = ((32 * (4 * mh + i)) | (8 * g)) ^ swzc;
  const int wce0 = ((32 * mte) | (8 * g)) ^ swzc;        // extra-tile cols (named)
  const int wce1 = ((32 * (mte + 1)) | (8 * g)) ^ swzc;
  const int rowE = (48 + n) * 256;                        // qt3 row base

  // pixel geometry: main trio + extra tile qt3 (c2 shift masking)
  int rcm[3], rc3;
#pragma unroll
  for (int qtl = 0; qtl < 3; ++qtl) {
    int p = 16 * (qb + qtl) + n;
    if (p < 100) { int r = p / 10; rcm[qtl] = r * 32 + (p - 10 * r); }
    else rcm[qtl] = 0x4000;
  }
  { int p = 48 + n; int r = p / 10; rc3 = r * 32 + (p - 10 * r); }

  // strided (c,px) decomposition for 500-elem copies
  const int cA = tid / 100, pA = tid - 100 * cA;
  const int cB = (tid + 256) / 100, pB = tid + 256 - 100 * cB;
  const int offA = pA * 12 + cA, offB = pB * 12 + cB;

  // zero ZROW of hA
  if (tid < 64) *(unsigned*)(lds + HA_OFF + ZROW_BASE + tid * 4) = 0;
  // load x state
  xs[offA] = x_in[(size_t)sample * 500 + tid];
  if (tid < 244) xs[offB] = x_in[(size_t)sample * 500 + tid + 256];
  // resident c7 bias (tiny)
  f32x4 b7v = fz;
  if (g == 0) b7v = *(const f32x4*)&b7p[0];
  else if (g == 1) b7v.x = b7p[4];
  __syncthreads();

  for (int step = 0; step < steps; ++step) {
    // ---- phase A: copy out states[step-1]; build im2col (r6-validated) ----
    if (step > 0) {
      size_t sb = 1024000u + ((size_t)(step - 1) * NSAMPLES + sample) * 500u;
      __builtin_nontemporal_store(xs[offA], &d_out[sb + tid]);
      if (tid < 244) __builtin_nontemporal_store(xs[offB], &d_out[sb + tid + 256]);
    }
    if (tid < 112) {
      const int p = tid;
      const bool pv = p < 100;
      const int pc = pv ? p : 99;
      const int r = pc / 10, c0 = pc - 10 * r;
      float val[48];
#pragma unroll
      for (int s = 0; s < 9; ++s) {
        const int dr = s / 3 - 1, dc = s % 3 - 1;
        f32x4 xv = fz; float x4v = 0.f;
        if (pv && (unsigned)(r + dr) < 10u && (unsigned)(c0 + dc) < 10u) {
          const float* xr = &xs[(p + dr * 10 + dc) * 12];
          xv = *(const f32x4*)xr; x4v = xr[4];
        }
        val[5*s+0] = xv.x; val[5*s+1] = xv.y; val[5*s+2] = xv.z;
        val[5*s+3] = xv.w; val[5*s+4] = x4v;
      }
      val[45] = val[46] = val[47] = 0.f;
      unsigned wd[24];
#pragma unroll
      for (int i = 0; i < 24; ++i) wd[i] = pk2(val[2*i], val[2*i+1]);
      const int swzr = (p & 7) << 4;
      char* arow = lds + A1_OFF + p * 128;
#pragma unroll
      for (int j = 0; j < 6; ++j) {
        u32x4 wv = {wd[4*j], wd[4*j+1], wd[4*j+2], wd[4*j+3]};
        *(u32x4*)(arow + ((16 * j) ^ swzr)) = wv;
      }
      u32x4 z4 = {0, 0, 0, 0};
      *(u32x4*)(arow + (96 ^ swzr)) = z4;
      *(u32x4*)(arow + (112 ^ swzr)) = z4;
    }
    __syncthreads();

    // ---- c1: A1 @ W1 (K=64) -> hA (trio x quad + qt3 x {mte,mte+1}) ----
    {
      f32x4 accm[4][3], acce0, acce1;
#pragma unroll
      for (int i = 0; i < 4; ++i) {
        f32x4 pb = *(const f32x4*)&b1p[16 * (4 * mh + i) + 4 * g];
#pragma unroll
        for (int qtl = 0; qtl < 3; ++qtl) accm[i][qtl] = pb;
      }
      acce0 = *(const f32x4*)&b1p[16 * mte + 4 * g];
      acce1 = *(const f32x4*)&b1p[16 * (mte + 1) + 4 * g];
#pragma unroll
      for (int kt = 0; kt < 2; ++kt) {
        bf16x8 Wf[4];
#pragma unroll
        for (int i = 0; i < 4; ++i)
          Wf[i] = *(const bf16x8*)&W1[((kt * 8 + 4 * mh + i) * 64 + l) * 8];
        bf16x8 We0 = *(const bf16x8*)&W1[((kt * 8 + mte) * 64 + l) * 8];
        bf16x8 We1 = *(const bf16x8*)&W1[((kt * 8 + mte + 1) * 64 + l) * 8];
        const char* src = lds + (rd1 ^ (kt << 6));
#pragma unroll
        for (int qtl = 0; qtl < 3; ++qtl) {
          bf16x8 Bf = *(const bf16x8*)(src + (qb + qtl) * 2048);
#pragma unroll
          for (int i = 0; i < 4; ++i) accm[i][qtl] = MFMA16(Wf[i], Bf, accm[i][qtl]);
        }
        bf16x8 Be = *(const bf16x8*)(src + 3 * 2048);
        acce0 = MFMA16(We0, Be, acce0);
        acce1 = MFMA16(We1, Be, acce1);
      }
#pragma unroll
      for (int qtl = 0; qtl < 3; ++qtl) {
        int row = (16 * (qb + qtl) + n) * 256;
#pragma unroll
        for (int i = 0; i < 4; ++i) {
          f32x4 v = accm[i][qtl];
          u32x2 wv = {pk2r(v.x, v.y), pk2r(v.z, v.w)};
          *(u32x2*)(lds + HA_OFF + row + wcolv[i]) = wv;
        }
      }
      {
        u32x2 w0 = {pk2r(acce0.x, acce0.y), pk2r(acce0.z, acce0.w)};
        *(u32x2*)(lds + HA_OFF + rowE + wce0) = w0;
        u32x2 w1 = {pk2r(acce1.x, acce1.y), pk2r(acce1.z, acce1.w)};
        *(u32x2*)(lds + HA_OFF + rowE + wce1) = w1;
      }
    }
    __syncthreads();

    // ---- c2: 3x3 shift-decomposed, runtime s-loop ----
    {
      f32x4 accm[4][3], acce0, acce1;
#pragma unroll
      for (int i = 0; i < 4; ++i) {
        f32x4 pb = *(const f32x4*)&b2p[16 * (4 * mh + i) + 4 * g];
#pragma unroll
        for (int qtl = 0; qtl < 3; ++qtl) accm[i][qtl] = pb;
      }
      acce0 = *(const f32x4*)&b2p[16 * mte + 4 * g];
      acce1 = *(const f32x4*)&b2p[16 * (mte + 1) + 4 * g];
#pragma unroll 1
      for (int s = 0; s < 9; ++s) {
        const int s3 = s / 3;
        const int dr = s3 - 1, dc = s - 3 * s3 - 1;
        const int ps = n + dr * 10 + dc;
        const int bs = HA_OFF + ps * 256 + (g16 ^ ((ps & 7) << 4));
        int vam[3], vae;
#pragma unroll
        for (int qtl = 0; qtl < 3; ++qtl) {
          bool ok = ((unsigned)((rcm[qtl] >> 5) + dr) < 10u) &&
                    ((unsigned)((rcm[qtl] & 31) + dc) < 10u);
          vam[qtl] = ok ? (bs + (qb + qtl) * 4096) : za;
        }
        {
          bool ok = ((unsigned)((rc3 >> 5) + dr) < 10u) &&
                    ((unsigned)((rc3 & 31) + dc) < 10u);
          vae = ok ? (bs + 3 * 4096) : za;
        }
        const short* Wsl = W2 + s * 16384;
#pragma unroll
        for (int kt = 0; kt < 4; ++kt) {
          bf16x8 Wf[4];
#pragma unroll
          for (int i = 0; i < 4; ++i)
            Wf[i] = *(const bf16x8*)&Wsl[((kt * 8 + 4 * mh + i) * 64 + l) * 8];
          bf16x8 We0 = *(const bf16x8*)&Wsl[((kt * 8 + mte) * 64 + l) * 8];
          bf16x8 We1 = *(const bf16x8*)&Wsl[((kt * 8 + mte + 1) * 64 + l) * 8];
#pragma unroll
          for (int qtl = 0; qtl < 3; ++qtl) {
            bf16x8 Bf = *(const bf16x8*)(lds + (vam[qtl] ^ (kt << 6)));
#pragma unroll
            for (int i = 0; i < 4; ++i) accm[i][qtl] = MFMA16(Wf[i], Bf, accm[i][qtl]);
          }
          bf16x8 Be = *(const bf16x8*)(lds + (vae ^ (kt << 6)));
          acce0 = MFMA16(We0, Be, acce0);
          acce1 = MFMA16(We1, Be, acce1);
        }
      }
#pragma unroll
      for (int qtl = 0; qtl < 3; ++qtl) {
        int row = (16 * (qb + qtl) + n) * 256;
#pragma unroll
        for (int i = 0; i < 4; ++i) {
          f32x4 v = accm[i][qtl];
          u32x2 wv = {pk2r(v.x, v.y), pk2r(v.z, v.w)};
          *(u32x2*)(lds + HB_OFF + row + wcolv[i]) = wv;
        }
      }
      {
        u32x2 w0 = {pk2r(acce0.x, acce0.y), pk2r(acce0.z, acce0.w)};
        *(u32x2*)(lds + HB_OFF + rowE + wce0) = w0;
        u32x2 w1 = {pk2r(acce1.x, acce1.y), pk2r(acce1.z, acce1.w)};
        *(u32x2*)(lds + HB_OFF + rowE + wce1) = w1;
      }
    }
    __syncthreads();

    // ---- c3..c6: runtime layer loop, ping-pong hB<->hA ----
#pragma unroll 1
    for (int li = 0; li < 4; ++li) {
      const float* bp = (li == 0) ? b3p : (li == 1) ? b4p : (li == 2) ? b5p : b6p;
      const int rdb = (li & 1) ? rdA : rdB;
      const int dsto = (li & 1) ? HB_OFF : HA_OFF;
      const short* Wp = W3 + li * 16384;
      f32x4 accm[4][3], acce0, acce1;
#pragma unroll
      for (int i = 0; i < 4; ++i) {
        f32x4 pb = *(const f32x4*)&bp[16 * (4 * mh + i) + 4 * g];
#pragma unroll
        for (int qtl = 0; qtl < 3; ++qtl) accm[i][qtl] = pb;
      }
      acce0 = *(const f32x4*)&bp[16 * mte + 4 * g];
      acce1 = *(const f32x4*)&bp[16 * (mte + 1) + 4 * g];
#pragma unroll
      for (int kt = 0; kt < 4; ++kt) {
        bf16x8 Wf[4];
#pragma unroll
        for (int i = 0; i < 4; ++i)
          Wf[i] = *(const bf16x8*)&Wp[((kt * 8 + 4 * mh + i) * 64 + l) * 8];
        bf16x8 We0 = *(const bf16x8*)&Wp[((kt * 8 + mte) * 64 + l) * 8];
        bf16x8 We1 = *(const bf16x8*)&Wp[((kt * 8 + mte + 1) * 64 + l) * 8];
        const char* src = lds + (rdb ^ (kt << 6));
#pragma unroll
        for (int qtl = 0; qtl < 3; ++qtl) {
          bf16x8 Bf = *(const bf16x8*)(src + (qb + qtl) * 4096);
#pragma unroll
          for (int i = 0; i < 4; ++i) accm[i][qtl] = MFMA16(Wf[i], Bf, accm[i][qtl]);
        }
        bf16x8 Be = *(const bf16x8*)(src + 3 * 4096);
        acce0 = MFMA16(We0, Be, acce0);
        acce1 = MFMA16(We1, Be, acce1);
      }
#pragma unroll
      for (int qtl = 0; qtl < 3; ++qtl) {
        int row = (16 * (qb + qtl) + n) * 256;
#pragma unroll
        for (int i = 0; i < 4; ++i) {
          f32x4 v = accm[i][qtl];
          u32x2 wv = {pk2r(v.x, v.y), pk2r(v.z, v.w)};
          *(u32x2*)(lds + dsto + row + wcolv[i]) = wv;
        }
      }
      {
        u32x2 w0 = {pk2r(acce0.x, acce0.y), pk2r(acce0.z, acce0.w)};
        *(u32x2*)(lds + dsto + rowE + wce0) = w0;
        u32x2 w1 = {pk2r(acce1.x, acce1.y), pk2r(acce1.z, acce1.w)};
        *(u32x2*)(lds + dsto + rowE + wce1) = w1;
      }
      __syncthreads();
    }

    // ---- c7 (128->5) + residual + softmax (r6-validated, W7f transient) ----
    {
      bf16x8 W7f[4];
#pragma unroll
      for (int kt = 0; kt < 4; ++kt)
        W7f[kt] = *(const bf16x8*)&W7[(kt * 64 + l) * 8];
      float invT = 1.f / fmaxf(1.f - (float)step / steps_f, 0.5f);
#pragma unroll
      for (int rep = 0; rep < 2; ++rep) {
        int qt = 2 * w + rep;
        if (qt < 7) {
          f32x4 a = b7v;
          int va7 = rdB + qt * 4096;
#pragma unroll
          for (int kt = 0; kt < 4; ++kt) {
            bf16x8 Bf = *(const bf16x8*)(lds + (va7 ^ (kt << 6)));
            a = MFMA16(W7f[kt], Bf, a);
          }
          float c4v = __shfl_xor(a.x, 16);
          int px = 16 * qt + n;
          if (g == 0 && px < 100) {
            float* xr = &xs[px * 12];
            f32x4 xo = *(f32x4*)xr; float x4 = xr[4];
            float v0 = (xo.x + a.x) * invT, v1 = (xo.y + a.y) * invT;
            float v2 = (xo.z + a.z) * invT, v3 = (xo.w + a.w) * invT;
            float v4 = (x4 + c4v) * invT;
            float m = fmaxf(fmaxf(fmaxf(v0, v1), fmaxf(v2, v3)), v4);
            float e0 = __expf(v0 - m), e1 = __expf(v1 - m), e2 = __expf(v2 - m);
            float e3 = __expf(v3 - m), e4 = __expf(v4 - m);
            float inv = 1.f / (e0 + e1 + e2 + e3 + e4);
            f32x4 pv = {e0 * inv, e1 * inv, e2 * inv, e3 * inv};
            *(f32x4*)xr = pv; xr[4] = e4 * inv;
          }
        }
      }
    }
    __syncthreads();
  }

  // ---- final outputs: x_final + states[steps-1] (nontemporal) ----
  {
    size_t sb = 1024000u + ((size_t)(steps - 1) * NSAMPLES + sample) * 500u;
    size_t fb = (size_t)sample * 500u;
    float vA = xs[offA];
    __builtin_nontemporal_store(vA, &d_out[fb + tid]);
    __builtin_nontemporal_store(vA, &d_out[sb + tid]);
    if (tid < 244) {
      float vB = xs[offB];
      __builtin_nontemporal_store(vB, &d_out[fb + tid + 256]);
      __builtin_nontemporal_store(vB, &d_out[sb + tid + 256]);
    }
  }
}

// ---------------- launch ----------------
extern "C" void kernel_launch(void* const* d_in, const int* in_sizes, int n_in,
                              void* d_out, int out_size, void* d_ws, size_t ws_size,
                              hipStream_t stream) {
  const float* x   = (const float*)d_in[0];
  const float* wp1 = (const float*)d_in[1];
  const float* bp1 = (const float*)d_in[2];
  const float* wp2 = (const float*)d_in[3];
  const float* bp2 = (const float*)d_in[4];
  const float* wp3 = (const float*)d_in[5];
  const float* bp3 = (const float*)d_in[6];
  const float* wu1 = (const float*)d_in[7];
  const float* bu1 = (const float*)d_in[8];
  const float* wu2 = (const float*)d_in[9];
  const float* bu2 = (const float*)d_in[10];
  const float* wu3 = (const float*)d_in[11];
  const float* bu3 = (const float*)d_in[12];
  const float* wu4 = (const float*)d_in[13];
  const float* bu4 = (const float*)d_in[14];
  const int* steps = (const int*)d_in[15];

  short* W1 = (short*)d_ws;          // [2][8][512]
  short* W2 = W1 + 8192;             // [36][8][512]
  short* W3 = W2 + 147456;           // 4 x [4][8][512] contiguous
  short* W4 = W3 + 16384;
  short* W5 = W4 + 16384;
  short* W6 = W5 + 16384;
  short* W7 = W6 + 16384;            // [4][1][512]

  prepack_kernel<<<(8192   + 255) / 256, 256, 0, stream>>>(wp1, W1, 1, 8, 45,   128, 8192);
  prepack_kernel<<<(147456 + 255) / 256, 256, 0, stream>>>(wp2, W2, 2, 8, 1152, 128, 147456);
  prepack_kernel<<<(16384  + 255) / 256, 256, 0, stream>>>(wp3, W3, 0, 8, 128,  128, 16384);
  prepack_kernel<<<(16384  + 255) / 256, 256, 0, stream>>>(wu1, W4, 0, 8, 128,  128, 16384);
  prepack_kernel<<<(16384  + 255) / 256, 256, 0, stream>>>(wu2, W5, 0, 8, 128,  128, 16384);
  prepack_kernel<<<(16384  + 255) / 256, 256, 0, stream>>>(wu3, W6, 0, 8, 128,  128, 16384);
  prepack_kernel<<<(2048   + 255) / 256, 256, 0, stream>>>(wu4, W7, 0, 1, 128,  5,   2048);

  nca_kernel<<<NSAMPLES, 256, 0, stream>>>(
      x, bp1, bp2, bp3, bu1, bu2, bu3, bu4,
      W1, W2, W3, W7, steps, (float*)d_out);
}

// Round 13
// 4594.912 us; speedup vs baseline: 36.4154x; 1.5072x over previous
//
#include <hip/hip_runtime.h>
#include <cstdint>
#include <cstddef>

// SokobanNCA v13: r6 dataflow exactly, with LDS shrunk 63->52.5KB so THREE
// blocks fit per CU (12 waves, 3/SIMD): h buffers 100 rows (no pad rows),
// qt-tile-6 reads clamped to a 256B zero row / writes to a 256B dump row via
// conditional bases; xs flat [5][100]. r6 was latency-bound with no pipe
// >50% busy -> +50% TLP and batches 4 -> 2.67.

#define NSAMPLES 2048
#define HA_OFF 0                 // 100 rows x 256B
#define HB_OFF 25600             // 100 rows x 256B (A1 aliases, 100x128B)
#define A1_OFF HB_OFF
#define ZB_OFF 51200             // 256B zeros (256-aligned: XOR-safe)
#define DP_OFF 51456             // 256B write dump
#define XS_OFF 51712             // 5*100 f32 = 2000B
#define LDS_TOTAL 53712

typedef __attribute__((ext_vector_type(8))) short bf16x8;
typedef __attribute__((ext_vector_type(4))) float f32x4;
typedef __attribute__((ext_vector_type(2))) unsigned int u32x2;
typedef __attribute__((ext_vector_type(4))) unsigned int u32x4;

#define MFMA16(A,B,C) __builtin_amdgcn_mfma_f32_16x16x32_bf16((A),(B),(C),0,0,0)

__device__ __forceinline__ unsigned pk2(float a, float b) {
  unsigned r;
  asm("v_cvt_pk_bf16_f32 %0, %1, %2" : "=v"(r) : "v"(a), "v"(b));
  return r;
}
__device__ __forceinline__ unsigned pk2r(float a, float b) {
  return pk2(fmaxf(a, 0.f), fmaxf(b, 0.f));
}

__device__ __forceinline__ short f2bf(float f) {
  unsigned u = __float_as_uint(f);
  return (short)((u + 0x7FFFu + ((u >> 16) & 1u)) >> 16);  // RNE
}

// ---------------- weight pre-pack (unchanged; validated r1-r12) ----------------
__global__ void prepack_kernel(const float* __restrict__ w, short* __restrict__ dst,
                               int mode, int ntc, int Kact, int Nact, int total) {
  int idx = blockIdx.x * 256 + threadIdx.x;
  if (idx >= total) return;
  int j = idx & 7, l = (idx >> 3) & 63, t = idx >> 9;
  int nt = t % ntc, kt = t / ntc;
  int kg = kt * 32 + (l >> 4) * 8 + j;
  int nn = nt * 16 + (l & 15);
  float v = 0.f;
  if (mode == 0) {
    if (kg < Kact && nn < Nact) v = w[nn * Kact + kg];
  } else if (mode == 1) {
    if (kg < 45) { int s = kg / 5, cin = kg - 5 * s; v = w[nn * 45 + cin * 9 + s]; }
  } else {
    int s = kt >> 2;
    int kk = (kt & 3) * 32 + (l >> 4) * 8 + j;
    v = w[nn * 1152 + kk * 9 + s];
  }
  dst[idx] = f2bf(v);
}

// ---------------- device helpers ----------------
__device__ __forceinline__ void load_w4(bf16x8 (&W)[2][4], const short* __restrict__ p,
                                        int w, int l) {
#pragma unroll
  for (int mt = 0; mt < 2; ++mt)
#pragma unroll
    for (int kt = 0; kt < 4; ++kt)
      W[mt][kt] = *(const bf16x8*)&p[((kt * 8 + 2 * w + mt) * 64 + l) * 8];
}
__device__ __forceinline__ void load_b(f32x4 (&pb)[2], const float* __restrict__ bp,
                                       int w, int g) {
  pb[0] = *(const f32x4*)&bp[16 * (2 * w) + 4 * g];
  pb[1] = *(const f32x4*)&bp[16 * (2 * w + 1) + 4 * g];
}

// 7-tile chain: qt 0..5 affine + clamped qt6 (rb6 = valid? base+24576 : ZB+g16)
__device__ __forceinline__ void chain7(const bf16x8 (&W)[2][4], const f32x4 (&pb)[2],
                                       const char* lds, int rdb, int rb6,
                                       f32x4 (&acc)[2][7]) {
#pragma unroll
  for (int qt = 0; qt < 7; ++qt) { acc[0][qt] = pb[0]; acc[1][qt] = pb[1]; }
#pragma unroll
  for (int kt = 0; kt < 4; ++kt) {
    const char* src = lds + (rdb ^ (kt << 6));
#pragma unroll
    for (int qt = 0; qt < 6; ++qt) {
      bf16x8 Bf = *(const bf16x8*)(src + qt * 4096);
      acc[0][qt] = MFMA16(W[0][kt], Bf, acc[0][qt]);
      acc[1][qt] = MFMA16(W[1][kt], Bf, acc[1][qt]);
    }
    bf16x8 B6 = *(const bf16x8*)(lds + (rb6 ^ (kt << 6)));
    acc[0][6] = MFMA16(W[0][kt], B6, acc[0][6]);
    acc[1][6] = MFMA16(W[1][kt], B6, acc[1][6]);
  }
}

// store qt 0..5 affine + qt6 to conditional base (dump when row invalid)
__device__ __forceinline__ void store7(const f32x4 (&acc)[2][7], char* lds,
                                       int wb0, int wb1, int w6b0, int w6b1) {
#pragma unroll
  for (int qt = 0; qt < 6; ++qt) {
    f32x4 v0 = acc[0][qt];
    u32x2 a = {pk2r(v0.x, v0.y), pk2r(v0.z, v0.w)};
    *(u32x2*)(lds + wb0 + qt * 4096) = a;
    f32x4 v1 = acc[1][qt];
    u32x2 b = {pk2r(v1.x, v1.y), pk2r(v1.z, v1.w)};
    *(u32x2*)(lds + wb1 + qt * 4096) = b;
  }
  {
    f32x4 v0 = acc[0][6];
    u32x2 a = {pk2r(v0.x, v0.y), pk2r(v0.z, v0.w)};
    *(u32x2*)(lds + w6b0) = a;
    f32x4 v1 = acc[1][6];
    u32x2 b = {pk2r(v1.x, v1.y), pk2r(v1.z, v1.w)};
    *(u32x2*)(lds + w6b1) = b;
  }
}

// ---------------- main kernel ----------------
__global__ __launch_bounds__(256, 2)
void nca_kernel(
    const float* __restrict__ x_in,
    const float* __restrict__ b1p, const float* __restrict__ b2p,
    const float* __restrict__ b3p, const float* __restrict__ b4p,
    const float* __restrict__ b5p, const float* __restrict__ b6p,
    const float* __restrict__ b7p,
    const short* __restrict__ W1, const short* __restrict__ W2,
    const short* __restrict__ W3,   // W3..W6 contiguous: W3 + li*16384
    const short* __restrict__ W7,
    const int* __restrict__ steps_ptr, float* __restrict__ d_out) {
  __shared__ __align__(16) char lds[LDS_TOTAL];
  float* xsf = (float*)(lds + XS_OFF);  // flat [c][p]: c*100+p

  const int tid = threadIdx.x;
  const int sample = blockIdx.x;
  const int w = tid >> 6;
  const int l = tid & 63;
  const int n = l & 15;
  const int g = l >> 4;
  const int g16 = g << 4;
  const int swzc = (n & 7) << 4;
  const int steps = *steps_ptr;
  const float steps_f = (float)steps;
  const f32x4 fz = {0.f, 0.f, 0.f, 0.f};

  // affine bases (layout as r6, minus pad rows)
  const int rdA = HA_OFF + n * 256 + (g16 ^ swzc);
  const int rdB = HB_OFF + n * 256 + (g16 ^ swzc);
  const int rd1 = A1_OFF + n * 128 + (g16 ^ swzc);
  const int zb  = ZB_OFF + g16;                 // zero-row read (XOR-safe)
  const bool v6 = (n < 4);                      // qt6 row 96+n valid iff n<4
  const int rb6A = v6 ? (rdA + 24576) : zb;
  const int rb6B = v6 ? (rdB + 24576) : zb;
  const int rb61 = v6 ? (rd1 + 12288) : zb;
  const int wcol0 = ((64 * w) | (8 * g)) ^ swzc;
  const int wcol1 = ((64 * w + 32) | (8 * g)) ^ swzc;
  const int wbA0 = HA_OFF + n * 256 + wcol0, wbA1 = HA_OFF + n * 256 + wcol1;
  const int wbB0 = HB_OFF + n * 256 + wcol0, wbB1 = HB_OFF + n * 256 + wcol1;
  const int w6A0 = v6 ? (wbA0 + 24576) : DP_OFF;
  const int w6A1 = v6 ? (wbA1 + 24576) : DP_OFF;
  const int w6B0 = v6 ? (wbB0 + 24576) : DP_OFF;
  const int w6B1 = v6 ? (wbB1 + 24576) : DP_OFF;

  // per-lane pixel geometry per q-tile (c2 shift masking)
  int rc[7];
#pragma unroll
  for (int qt = 0; qt < 7; ++qt) {
    int p = 16 * qt + n;
    if (p < 100) { int r = p / 10; rc[qt] = r * 32 + (p - 10 * r); }
    else rc[qt] = 0x4000;
  }

  // zero the ZB row (256B)
  if (tid < 64) *(unsigned*)(lds + ZB_OFF + tid * 4) = 0;
  // load x state (flat)
  xsf[tid < 500 ? tid : 500 - 1] = x_in[(size_t)sample * 500 + (tid < 500 ? tid : 499)];
  if (tid < 244) xsf[tid + 256] = x_in[(size_t)sample * 500 + tid + 256];
  // resident c7 bias
  f32x4 b7v = fz;
  if (g == 0) b7v = *(const f32x4*)&b7p[0];
  else if (g == 1) b7v.x = b7p[4];
  __syncthreads();

  for (int step = 0; step < steps; ++step) {
    // ---- phase A: copy out states[step-1] (linear!); build im2col ----
    if (step > 0) {
      size_t sb = 1024000u + ((size_t)(step - 1) * NSAMPLES + sample) * 500u;
      if (tid < 500) __builtin_nontemporal_store(xsf[tid], &d_out[sb + tid]);
      if (tid < 244) __builtin_nontemporal_store(xsf[tid + 256], &d_out[sb + tid + 256]);
    }
    if (tid < 100) {
      const int p = tid;
      const int r = p / 10, c0 = p - 10 * r;
      float val[48];
#pragma unroll
      for (int s = 0; s < 9; ++s) {
        const int dr = s / 3 - 1, dc = s % 3 - 1;
        bool okp = ((unsigned)(r + dr) < 10u) && ((unsigned)(c0 + dc) < 10u);
        int p2 = okp ? (p + dr * 10 + dc) : p;
        float m = okp ? 1.f : 0.f;
        val[5*s+0] = xsf[p2] * m;
        val[5*s+1] = xsf[100 + p2] * m;
        val[5*s+2] = xsf[200 + p2] * m;
        val[5*s+3] = xsf[300 + p2] * m;
        val[5*s+4] = xsf[400 + p2] * m;
      }
      val[45] = val[46] = val[47] = 0.f;
      unsigned wd[24];
#pragma unroll
      for (int i = 0; i < 24; ++i) wd[i] = pk2(val[2*i], val[2*i+1]);
      const int swzr = (p & 7) << 4;
      char* arow = lds + A1_OFF + p * 128;
#pragma unroll
      for (int j = 0; j < 6; ++j) {
        u32x4 wv = {wd[4*j], wd[4*j+1], wd[4*j+2], wd[4*j+3]};
        *(u32x4*)(arow + ((16 * j) ^ swzr)) = wv;
      }
      u32x4 z4 = {0, 0, 0, 0};
      *(u32x4*)(arow + (96 ^ swzr)) = z4;
      *(u32x4*)(arow + (112 ^ swzr)) = z4;
    }
    __syncthreads();

    // ---- c1: A1 @ W1 (K=64) -> hA, transient weights ----
    {
      bf16x8 Wf[2][2];
#pragma unroll
      for (int mt = 0; mt < 2; ++mt)
#pragma unroll
        for (int kt = 0; kt < 2; ++kt)
          Wf[mt][kt] = *(const bf16x8*)&W1[((kt * 8 + 2 * w + mt) * 64 + l) * 8];
      f32x4 pb[2];
      load_b(pb, b1p, w, g);
      f32x4 acc[2][7];
#pragma unroll
      for (int qt = 0; qt < 7; ++qt) { acc[0][qt] = pb[0]; acc[1][qt] = pb[1]; }
#pragma unroll
      for (int kt = 0; kt < 2; ++kt) {
        const char* src = lds + (rd1 ^ (kt << 6));
#pragma unroll
        for (int qt = 0; qt < 6; ++qt) {
          bf16x8 Bf = *(const bf16x8*)(src + qt * 2048);
          acc[0][qt] = MFMA16(Wf[0][kt], Bf, acc[0][qt]);
          acc[1][qt] = MFMA16(Wf[1][kt], Bf, acc[1][qt]);
        }
        bf16x8 B6 = *(const bf16x8*)(lds + (rb61 ^ (kt << 6)));
        acc[0][6] = MFMA16(Wf[0][kt], B6, acc[0][6]);
        acc[1][6] = MFMA16(Wf[1][kt], B6, acc[1][6]);
      }
      store7(acc, lds, wbA0, wbA1, w6A0, w6A1);
    }
    __syncthreads();

    // ---- c2: 3x3 shift-decomposed, runtime s-loop (ok-mask handles qt6) ----
    {
      f32x4 acc[2][7];
      {
        f32x4 pb[2];
        load_b(pb, b2p, w, g);
#pragma unroll
        for (int qt = 0; qt < 7; ++qt) { acc[0][qt] = pb[0]; acc[1][qt] = pb[1]; }
      }
#pragma unroll 1
      for (int s = 0; s < 9; ++s) {
        const int s3 = s / 3;
        const int dr = s3 - 1, dc = s - 3 * s3 - 1;
        bf16x8 Wf[2][4];
        load_w4(Wf, W2 + s * 16384, w, l);
        const int ps = n + dr * 10 + dc;
        const int bs = HA_OFF + ps * 256 + (g16 ^ ((ps & 7) << 4));
#pragma unroll
        for (int qt = 0; qt < 7; ++qt) {
          bool ok = ((unsigned)((rc[qt] >> 5) + dr) < 10u) &&
                    ((unsigned)((rc[qt] & 31) + dc) < 10u);
          int va = ok ? (bs + qt * 4096) : zb;
#pragma unroll
          for (int kt = 0; kt < 4; ++kt) {
            bf16x8 Bf = *(const bf16x8*)(lds + (va ^ (kt << 6)));
            acc[0][qt] = MFMA16(Wf[0][kt], Bf, acc[0][qt]);
            acc[1][qt] = MFMA16(Wf[1][kt], Bf, acc[1][qt]);
          }
        }
      }
      store7(acc, lds, wbB0, wbB1, w6B0, w6B1);
    }
    __syncthreads();

    // ---- c3..c6: runtime layer loop, ping-pong hB<->hA ----
#pragma unroll 1
    for (int li = 0; li < 4; ++li) {
      const float* bp = (li == 0) ? b3p : (li == 1) ? b4p : (li == 2) ? b5p : b6p;
      const int rdb = (li & 1) ? rdA : rdB;
      const int rb6 = (li & 1) ? rb6A : rb6B;
      const int wb0 = (li & 1) ? wbB0 : wbA0;
      const int wb1 = (li & 1) ? wbB1 : wbA1;
      const int w60 = (li & 1) ? w6B0 : w6A0;
      const int w61 = (li & 1) ? w6B1 : w6A1;
      bf16x8 Wf[2][4];
      load_w4(Wf, W3 + li * 16384, w, l);
      f32x4 pb[2];
      load_b(pb, bp, w, g);
      f32x4 acc[2][7];
      chain7(Wf, pb, lds, rdb, rb6, acc);
      store7(acc, lds, wb0, wb1, w60, w61);
      __syncthreads();
    }

    // ---- c7 (128->5) + residual + softmax ----
    {
      bf16x8 W7f[4];
#pragma unroll
      for (int kt = 0; kt < 4; ++kt)
        W7f[kt] = *(const bf16x8*)&W7[(kt * 64 + l) * 8];
      float invT = 1.f / fmaxf(1.f - (float)step / steps_f, 0.5f);
#pragma unroll
      for (int rep = 0; rep < 2; ++rep) {
        int qt = 2 * w + rep;
        if (qt < 7) {
          f32x4 a = b7v;
          int va7 = (qt < 6 || v6) ? (rdB + qt * 4096) : zb;
#pragma unroll
          for (int kt = 0; kt < 4; ++kt) {
            bf16x8 Bf = *(const bf16x8*)(lds + (va7 ^ (kt << 6)));
            a = MFMA16(W7f[kt], Bf, a);
          }
          float c4v = __shfl_xor(a.x, 16);
          int px = 16 * qt + n;
          if (g == 0 && px < 100) {
            float* xc = xsf + px;
            float x0 = xc[0], x1 = xc[100], x2 = xc[200], x3 = xc[300], x4 = xc[400];
            float v0 = (x0 + a.x) * invT, v1 = (x1 + a.y) * invT;
            float v2 = (x2 + a.z) * invT, v3 = (x3 + a.w) * invT;
            float v4 = (x4 + c4v) * invT;
            float m = fmaxf(fmaxf(fmaxf(v0, v1), fmaxf(v2, v3)), v4);
            float e0 = __expf(v0 - m), e1 = __expf(v1 - m), e2 = __expf(v2 - m);
            float e3 = __expf(v3 - m), e4 = __expf(v4 - m);
            float inv = 1.f / (e0 + e1 + e2 + e3 + e4);
            xc[0] = e0 * inv; xc[100] = e1 * inv; xc[200] = e2 * inv;
            xc[300] = e3 * inv; xc[400] = e4 * inv;
          }
        }
      }
    }
    __syncthreads();
  }

  // ---- final outputs: x_final + states[steps-1] (nontemporal, linear) ----
  {
    size_t sb = 1024000u + ((size_t)(steps - 1) * NSAMPLES + sample) * 500u;
    size_t fb = (size_t)sample * 500u;
    if (tid < 500) {
      float v = xsf[tid];
      __builtin_nontemporal_store(v, &d_out[fb + tid]);
      __builtin_nontemporal_store(v, &d_out[sb + tid]);
    }
    if (tid < 244) {
      float v = xsf[tid + 256];
      __builtin_nontemporal_store(v, &d_out[fb + tid + 256]);
      __builtin_nontemporal_store(v, &d_out[sb + tid + 256]);
    }
  }
}

// ---------------- launch ----------------
extern "C" void kernel_launch(void* const* d_in, const int* in_sizes, int n_in,
                              void* d_out, int out_size, void* d_ws, size_t ws_size,
                              hipStream_t stream) {
  const float* x   = (const float*)d_in[0];
  const float* wp1 = (const float*)d_in[1];
  const float* bp1 = (const float*)d_in[2];
  const float* wp2 = (const float*)d_in[3];
  const float* bp2 = (const float*)d_in[4];
  const float* wp3 = (const float*)d_in[5];
  const float* bp3 = (const float*)d_in[6];
  const float* wu1 = (const float*)d_in[7];
  const float* bu1 = (const float*)d_in[8];
  const float* wu2 = (const float*)d_in[9];
  const float* bu2 = (const float*)d_in[10];
  const float* wu3 = (const float*)d_in[11];
  const float* bu3 = (const float*)d_in[12];
  const float* wu4 = (const float*)d_in[13];
  const float* bu4 = (const float*)d_in[14];
  const int* steps = (const int*)d_in[15];

  short* W1 = (short*)d_ws;          // [2][8][512]
  short* W2 = W1 + 8192;             // [36][8][512]
  short* W3 = W2 + 147456;           // 4 x [4][8][512] contiguous
  short* W4 = W3 + 16384;
  short* W5 = W4 + 16384;
  short* W6 = W5 + 16384;
  short* W7 = W6 + 16384;            // [4][1][512]

  prepack_kernel<<<(8192   + 255) / 256, 256, 0, stream>>>(wp1, W1, 1, 8, 45,   128, 8192);
  prepack_kernel<<<(147456 + 255) / 256, 256, 0, stream>>>(wp2, W2, 2, 8, 1152, 128, 147456);
  prepack_kernel<<<(16384  + 255) / 256, 256, 0, stream>>>(wp3, W3, 0, 8, 128,  128, 16384);
  prepack_kernel<<<(16384  + 255) / 256, 256, 0, stream>>>(wu1, W4, 0, 8, 128,  128, 16384);
  prepack_kernel<<<(16384  + 255) / 256, 256, 0, stream>>>(wu2, W5, 0, 8, 128,  128, 16384);
  prepack_kernel<<<(16384  + 255) / 256, 256, 0, stream>>>(wu3, W6, 0, 8, 128,  128, 16384);
  prepack_kernel<<<(2048   + 255) / 256, 256, 0, stream>>>(wu4, W7, 0, 1, 128,  5,   2048);

  nca_kernel<<<NSAMPLES, 256, 0, stream>>>(
      x, bp1, bp2, bp3, bu1, bu2, bu3, bu4,
      W1, W2, W3, W7, steps, (float*)d_out);
}

// Round 14
// 4589.840 us; speedup vs baseline: 36.4557x; 1.0011x over previous
//
#include <hip/hip_runtime.h>
#include <cstdint>
#include <cstddef>

// SokobanNCA v14: r13 dataflow with a SINGLE in-place h buffer. Every layer
// fully accumulates in registers before storing, so read-all -> barrier ->
// store-in-place -> barrier is race-free. LDS: h 25,600 + A1 12,800 + ZB 256
// + xs 2,000 = 40,656 B -> 40,960 at any granule <= 4KB -> FOUR blocks/CU
// (4 x 40,960 = 163,840 = full 160KiB pool; VGPR 124x4 = 496 <= 512 pool).
// 13 barriers/step (in-place needs read/store split), covered by 4-block TLP.

#define NSAMPLES 2048
#define H_OFF  0                 // 100 rows x 256B = 25,600
#define A1_OFF 25600             // 100 rows x 128B = 12,800
#define ZB_OFF 38400             // 256B zeros (256-aligned: XOR-safe)
#define XS_OFF 38656             // 500 f32 = 2,000B
#define LDS_TOTAL 40656

typedef __attribute__((ext_vector_type(8))) short bf16x8;
typedef __attribute__((ext_vector_type(4))) float f32x4;
typedef __attribute__((ext_vector_type(2))) unsigned int u32x2;
typedef __attribute__((ext_vector_type(4))) unsigned int u32x4;

#define MFMA16(A,B,C) __builtin_amdgcn_mfma_f32_16x16x32_bf16((A),(B),(C),0,0,0)

__device__ __forceinline__ unsigned pk2(float a, float b) {
  unsigned r;
  asm("v_cvt_pk_bf16_f32 %0, %1, %2" : "=v"(r) : "v"(a), "v"(b));
  return r;
}
__device__ __forceinline__ unsigned pk2r(float a, float b) {
  return pk2(fmaxf(a, 0.f), fmaxf(b, 0.f));
}

__device__ __forceinline__ short f2bf(float f) {
  unsigned u = __float_as_uint(f);
  return (short)((u + 0x7FFFu + ((u >> 16) & 1u)) >> 16);  // RNE
}

// ---------------- weight pre-pack (unchanged; validated r1-r13) ----------------
__global__ void prepack_kernel(const float* __restrict__ w, short* __restrict__ dst,
                               int mode, int ntc, int Kact, int Nact, int total) {
  int idx = blockIdx.x * 256 + threadIdx.x;
  if (idx >= total) return;
  int j = idx & 7, l = (idx >> 3) & 63, t = idx >> 9;
  int nt = t % ntc, kt = t / ntc;
  int kg = kt * 32 + (l >> 4) * 8 + j;
  int nn = nt * 16 + (l & 15);
  float v = 0.f;
  if (mode == 0) {
    if (kg < Kact && nn < Nact) v = w[nn * Kact + kg];
  } else if (mode == 1) {
    if (kg < 45) { int s = kg / 5, cin = kg - 5 * s; v = w[nn * 45 + cin * 9 + s]; }
  } else {
    int s = kt >> 2;
    int kk = (kt & 3) * 32 + (l >> 4) * 8 + j;
    v = w[nn * 1152 + kk * 9 + s];
  }
  dst[idx] = f2bf(v);
}

// ---------------- device helpers ----------------
__device__ __forceinline__ void load_w4(bf16x8 (&W)[2][4], const short* __restrict__ p,
                                        int w, int l) {
#pragma unroll
  for (int mt = 0; mt < 2; ++mt)
#pragma unroll
    for (int kt = 0; kt < 4; ++kt)
      W[mt][kt] = *(const bf16x8*)&p[((kt * 8 + 2 * w + mt) * 64 + l) * 8];
}
__device__ __forceinline__ void load_b(f32x4 (&pb)[2], const float* __restrict__ bp,
                                       int w, int g) {
  pb[0] = *(const f32x4*)&bp[16 * (2 * w) + 4 * g];
  pb[1] = *(const f32x4*)&bp[16 * (2 * w + 1) + 4 * g];
}

// 7-tile read chain: qt 0..5 affine + clamped qt6 (rb6 = v6? rd+24576 : ZB+g16)
__device__ __forceinline__ void chain7(const bf16x8 (&W)[2][4], const f32x4 (&pb)[2],
                                       const char* lds, int rdb, int rb6,
                                       f32x4 (&acc)[2][7]) {
#pragma unroll
  for (int qt = 0; qt < 7; ++qt) { acc[0][qt] = pb[0]; acc[1][qt] = pb[1]; }
#pragma unroll
  for (int kt = 0; kt < 4; ++kt) {
    const char* src = lds + (rdb ^ (kt << 6));
#pragma unroll
    for (int qt = 0; qt < 6; ++qt) {
      bf16x8 Bf = *(const bf16x8*)(src + qt * 4096);
      acc[0][qt] = MFMA16(W[0][kt], Bf, acc[0][qt]);
      acc[1][qt] = MFMA16(W[1][kt], Bf, acc[1][qt]);
    }
    bf16x8 B6 = *(const bf16x8*)(lds + (rb6 ^ (kt << 6)));
    acc[0][6] = MFMA16(W[0][kt], B6, acc[0][6]);
    acc[1][6] = MFMA16(W[1][kt], B6, acc[1][6]);
  }
}

// store qt 0..5 affine + qt6 predicated on v6 (rows 96+n valid iff n<4)
__device__ __forceinline__ void store7(const f32x4 (&acc)[2][7], char* lds,
                                       int wb0, int wb1, bool v6) {
#pragma unroll
  for (int qt = 0; qt < 6; ++qt) {
    f32x4 v0 = acc[0][qt];
    u32x2 a = {pk2r(v0.x, v0.y), pk2r(v0.z, v0.w)};
    *(u32x2*)(lds + wb0 + qt * 4096) = a;
    f32x4 v1 = acc[1][qt];
    u32x2 b = {pk2r(v1.x, v1.y), pk2r(v1.z, v1.w)};
    *(u32x2*)(lds + wb1 + qt * 4096) = b;
  }
  if (v6) {
    f32x4 v0 = acc[0][6];
    u32x2 a = {pk2r(v0.x, v0.y), pk2r(v0.z, v0.w)};
    *(u32x2*)(lds + wb0 + 24576) = a;
    f32x4 v1 = acc[1][6];
    u32x2 b = {pk2r(v1.x, v1.y), pk2r(v1.z, v1.w)};
    *(u32x2*)(lds + wb1 + 24576) = b;
  }
}

// ---------------- main kernel ----------------
__global__ __launch_bounds__(256, 2)
void nca_kernel(
    const float* __restrict__ x_in,
    const float* __restrict__ b1p, const float* __restrict__ b2p,
    const float* __restrict__ b3p, const float* __restrict__ b4p,
    const float* __restrict__ b5p, const float* __restrict__ b6p,
    const float* __restrict__ b7p,
    const short* __restrict__ W1, const short* __restrict__ W2,
    const short* __restrict__ W3,   // W3..W6 contiguous: W3 + li*16384
    const short* __restrict__ W7,
    const int* __restrict__ steps_ptr, float* __restrict__ d_out) {
  __shared__ __align__(16) char lds[LDS_TOTAL];
  float* xsf = (float*)(lds + XS_OFF);  // flat [c][p]: c*100+p

  const int tid = threadIdx.x;
  const int sample = blockIdx.x;
  const int w = tid >> 6;
  const int l = tid & 63;
  const int n = l & 15;
  const int g = l >> 4;
  const int g16 = g << 4;
  const int swzc = (n & 7) << 4;
  const int steps = *steps_ptr;
  const float steps_f = (float)steps;
  const f32x4 fz = {0.f, 0.f, 0.f, 0.f};

  // affine bases (single h buffer)
  const int rd  = H_OFF + n * 256 + (g16 ^ swzc);
  const int rd1 = A1_OFF + n * 128 + (g16 ^ swzc);
  const int zb  = ZB_OFF + g16;                 // zero-row read (XOR-safe)
  const bool v6 = (n < 4);                      // qt6 row 96+n valid iff n<4
  const int rb6  = v6 ? (rd + 24576) : zb;
  const int rb61 = v6 ? (rd1 + 12288) : zb;
  const int wcol0 = ((64 * w) | (8 * g)) ^ swzc;
  const int wcol1 = ((64 * w + 32) | (8 * g)) ^ swzc;
  const int wb0 = H_OFF + n * 256 + wcol0;
  const int wb1 = H_OFF + n * 256 + wcol1;

  // per-lane pixel geometry per q-tile (c2 shift masking)
  int rc[7];
#pragma unroll
  for (int qt = 0; qt < 7; ++qt) {
    int p = 16 * qt + n;
    if (p < 100) { int r = p / 10; rc[qt] = r * 32 + (p - 10 * r); }
    else rc[qt] = 0x4000;
  }

  // zero the ZB row (256B)
  if (tid < 64) *(unsigned*)(lds + ZB_OFF + tid * 4) = 0;
  // load x state (flat)
  if (tid < 500) xsf[tid] = x_in[(size_t)sample * 500 + tid];
  if (tid < 244) xsf[tid + 256] = x_in[(size_t)sample * 500 + tid + 256];
  // resident c7 bias
  f32x4 b7v = fz;
  if (g == 0) b7v = *(const f32x4*)&b7p[0];
  else if (g == 1) b7v.x = b7p[4];
  __syncthreads();

  for (int step = 0; step < steps; ++step) {
    // ---- phase A: copy out states[step-1] (linear); build im2col -> A1 ----
    if (step > 0) {
      size_t sb = 1024000u + ((size_t)(step - 1) * NSAMPLES + sample) * 500u;
      if (tid < 500) __builtin_nontemporal_store(xsf[tid], &d_out[sb + tid]);
      if (tid < 244) __builtin_nontemporal_store(xsf[tid + 256], &d_out[sb + tid + 256]);
    }
    if (tid < 100) {
      const int p = tid;
      const int r = p / 10, c0 = p - 10 * r;
      float val[48];
#pragma unroll
      for (int s = 0; s < 9; ++s) {
        const int dr = s / 3 - 1, dc = s % 3 - 1;
        bool okp = ((unsigned)(r + dr) < 10u) && ((unsigned)(c0 + dc) < 10u);
        int p2 = okp ? (p + dr * 10 + dc) : p;
        float m = okp ? 1.f : 0.f;
        val[5*s+0] = xsf[p2] * m;
        val[5*s+1] = xsf[100 + p2] * m;
        val[5*s+2] = xsf[200 + p2] * m;
        val[5*s+3] = xsf[300 + p2] * m;
        val[5*s+4] = xsf[400 + p2] * m;
      }
      val[45] = val[46] = val[47] = 0.f;
      unsigned wd[24];
#pragma unroll
      for (int i = 0; i < 24; ++i) wd[i] = pk2(val[2*i], val[2*i+1]);
      const int swzr = (p & 7) << 4;
      char* arow = lds + A1_OFF + p * 128;
#pragma unroll
      for (int j = 0; j < 6; ++j) {
        u32x4 wv = {wd[4*j], wd[4*j+1], wd[4*j+2], wd[4*j+3]};
        *(u32x4*)(arow + ((16 * j) ^ swzr)) = wv;
      }
      u32x4 z4 = {0, 0, 0, 0};
      *(u32x4*)(arow + (96 ^ swzr)) = z4;
      *(u32x4*)(arow + (112 ^ swzr)) = z4;
    }
    __syncthreads();

    // ---- c1: A1 @ W1 (K=64) -> h (A1 separate: store directly) ----
    {
      bf16x8 Wf[2][2];
#pragma unroll
      for (int mt = 0; mt < 2; ++mt)
#pragma unroll
        for (int kt = 0; kt < 2; ++kt)
          Wf[mt][kt] = *(const bf16x8*)&W1[((kt * 8 + 2 * w + mt) * 64 + l) * 8];
      f32x4 pb[2];
      load_b(pb, b1p, w, g);
      f32x4 acc[2][7];
#pragma unroll
      for (int qt = 0; qt < 7; ++qt) { acc[0][qt] = pb[0]; acc[1][qt] = pb[1]; }
#pragma unroll
      for (int kt = 0; kt < 2; ++kt) {
        const char* src = lds + (rd1 ^ (kt << 6));
#pragma unroll
        for (int qt = 0; qt < 6; ++qt) {
          bf16x8 Bf = *(const bf16x8*)(src + qt * 2048);
          acc[0][qt] = MFMA16(Wf[0][kt], Bf, acc[0][qt]);
          acc[1][qt] = MFMA16(Wf[1][kt], Bf, acc[1][qt]);
        }
        bf16x8 B6 = *(const bf16x8*)(lds + (rb61 ^ (kt << 6)));
        acc[0][6] = MFMA16(Wf[0][kt], B6, acc[0][6]);
        acc[1][6] = MFMA16(Wf[1][kt], B6, acc[1][6]);
      }
      store7(acc, lds, wb0, wb1, v6);
    }
    __syncthreads();

    // ---- c2: 3x3 shift-decomposed, in-place (read-all, barrier, store) ----
    {
      f32x4 acc[2][7];
      {
        f32x4 pb[2];
        load_b(pb, b2p, w, g);
#pragma unroll
        for (int qt = 0; qt < 7; ++qt) { acc[0][qt] = pb[0]; acc[1][qt] = pb[1]; }
      }
#pragma unroll 1
      for (int s = 0; s < 9; ++s) {
        const int s3 = s / 3;
        const int dr = s3 - 1, dc = s - 3 * s3 - 1;
        bf16x8 Wf[2][4];
        load_w4(Wf, W2 + s * 16384, w, l);
        const int ps = n + dr * 10 + dc;
        const int bs = H_OFF + ps * 256 + (g16 ^ ((ps & 7) << 4));
#pragma unroll
        for (int qt = 0; qt < 7; ++qt) {
          bool ok = ((unsigned)((rc[qt] >> 5) + dr) < 10u) &&
                    ((unsigned)((rc[qt] & 31) + dc) < 10u);
          int va = ok ? (bs + qt * 4096) : zb;
#pragma unroll
          for (int kt = 0; kt < 4; ++kt) {
            bf16x8 Bf = *(const bf16x8*)(lds + (va ^ (kt << 6)));
            acc[0][qt] = MFMA16(Wf[0][kt], Bf, acc[0][qt]);
            acc[1][qt] = MFMA16(Wf[1][kt], Bf, acc[1][qt]);
          }
        }
      }
      __syncthreads();                 // all reads of h complete
      store7(acc, lds, wb0, wb1, v6);  // in-place overwrite
    }
    __syncthreads();

    // ---- c3..c6: in-place 1x1 layers (read-all, barrier, store, barrier) ----
#pragma unroll 1
    for (int li = 0; li < 4; ++li) {
      const float* bp = (li == 0) ? b3p : (li == 1) ? b4p : (li == 2) ? b5p : b6p;
      bf16x8 Wf[2][4];
      load_w4(Wf, W3 + li * 16384, w, l);
      f32x4 pb[2];
      load_b(pb, bp, w, g);
      f32x4 acc[2][7];
      chain7(Wf, pb, lds, rd, rb6, acc);
      __syncthreads();
      store7(acc, lds, wb0, wb1, v6);
      __syncthreads();
    }

    // ---- c7 (128->5) + residual + softmax ----
    {
      bf16x8 W7f[4];
#pragma unroll
      for (int kt = 0; kt < 4; ++kt)
        W7f[kt] = *(const bf16x8*)&W7[(kt * 64 + l) * 8];
      float invT = 1.f / fmaxf(1.f - (float)step / steps_f, 0.5f);
#pragma unroll
      for (int rep = 0; rep < 2; ++rep) {
        int qt = 2 * w + rep;
        if (qt < 7) {
          f32x4 a = b7v;
          int va7 = (qt < 6 || v6) ? (rd + qt * 4096) : zb;
#pragma unroll
          for (int kt = 0; kt < 4; ++kt) {
            bf16x8 Bf = *(const bf16x8*)(lds + (va7 ^ (kt << 6)));
            a = MFMA16(W7f[kt], Bf, a);
          }
          float c4v = __shfl_xor(a.x, 16);
          int px = 16 * qt + n;
          if (g == 0 && px < 100) {
            float* xc = xsf + px;
            float x0 = xc[0], x1 = xc[100], x2 = xc[200], x3 = xc[300], x4 = xc[400];
            float v0 = (x0 + a.x) * invT, v1 = (x1 + a.y) * invT;
            float v2 = (x2 + a.z) * invT, v3 = (x3 + a.w) * invT;
            float v4 = (x4 + c4v) * invT;
            float m = fmaxf(fmaxf(fmaxf(v0, v1), fmaxf(v2, v3)), v4);
            float e0 = __expf(v0 - m), e1 = __expf(v1 - m), e2 = __expf(v2 - m);
            float e3 = __expf(v3 - m), e4 = __expf(v4 - m);
            float inv = 1.f / (e0 + e1 + e2 + e3 + e4);
            xc[0] = e0 * inv; xc[100] = e1 * inv; xc[200] = e2 * inv;
            xc[300] = e3 * inv; xc[400] = e4 * inv;
          }
        }
      }
    }
    __syncthreads();
  }

  // ---- final outputs: x_final + states[steps-1] (nontemporal, linear) ----
  {
    size_t sb = 1024000u + ((size_t)(steps - 1) * NSAMPLES + sample) * 500u;
    size_t fb = (size_t)sample * 500u;
    if (tid < 500) {
      float v = xsf[tid];
      __builtin_nontemporal_store(v, &d_out[fb + tid]);
      __builtin_nontemporal_store(v, &d_out[sb + tid]);
    }
    if (tid < 244) {
      float v = xsf[tid + 256];
      __builtin_nontemporal_store(v, &d_out[fb + tid + 256]);
      __builtin_nontemporal_store(v, &d_out[sb + tid + 256]);
    }
  }
}

// ---------------- launch ----------------
extern "C" void kernel_launch(void* const* d_in, const int* in_sizes, int n_in,
                              void* d_out, int out_size, void* d_ws, size_t ws_size,
                              hipStream_t stream) {
  const float* x   = (const float*)d_in[0];
  const float* wp1 = (const float*)d_in[1];
  const float* bp1 = (const float*)d_in[2];
  const float* wp2 = (const float*)d_in[3];
  const float* bp2 = (const float*)d_in[4];
  const float* wp3 = (const float*)d_in[5];
  const float* bp3 = (const float*)d_in[6];
  const float* wu1 = (const float*)d_in[7];
  const float* bu1 = (const float*)d_in[8];
  const float* wu2 = (const float*)d_in[9];
  const float* bu2 = (const float*)d_in[10];
  const float* wu3 = (const float*)d_in[11];
  const float* bu3 = (const float*)d_in[12];
  const float* wu4 = (const float*)d_in[13];
  const float* bu4 = (const float*)d_in[14];
  const int* steps = (const int*)d_in[15];

  short* W1 = (short*)d_ws;          // [2][8][512]
  short* W2 = W1 + 8192;             // [36][8][512]
  short* W3 = W2 + 147456;           // 4 x [4][8][512] contiguous
  short* W4 = W3 + 16384;
  short* W5 = W4 + 16384;
  short* W6 = W5 + 16384;
  short* W7 = W6 + 16384;            // [4][1][512]

  prepack_kernel<<<(8192   + 255) / 256, 256, 0, stream>>>(wp1, W1, 1, 8, 45,   128, 8192);
  prepack_kernel<<<(147456 + 255) / 256, 256, 0, stream>>>(wp2, W2, 2, 8, 1152, 128, 147456);
  prepack_kernel<<<(16384  + 255) / 256, 256, 0, stream>>>(wp3, W3, 0, 8, 128,  128, 16384);
  prepack_kernel<<<(16384  + 255) / 256, 256, 0, stream>>>(wu1, W4, 0, 8, 128,  128, 16384);
  prepack_kernel<<<(16384  + 255) / 256, 256, 0, stream>>>(wu2, W5, 0, 8, 128,  128, 16384);
  prepack_kernel<<<(16384  + 255) / 256, 256, 0, stream>>>(wu3, W6, 0, 8, 128,  128, 16384);
  prepack_kernel<<<(2048   + 255) / 256, 256, 0, stream>>>(wu4, W7, 0, 1, 128,  5,   2048);

  nca_kernel<<<NSAMPLES, 256, 0, stream>>>(
      x, bp1, bp2, bp3, bu1, bu2, bu3, bu4,
      W1, W2, W3, W7, steps, (float*)d_out);
}